// Round 4
// baseline (753.476 us; speedup 1.0000x reference)
//
#include <hip/hip_runtime.h>

#define C 64

// ---------------------------------------------------------------------------
// CSR build (no float atomics), then ONE fused voxel-centric pass with
// wave-per-voxel (64 lanes = 64 channels):
//  1. memset counts
//  2. hist:   counts[v]++ per point           (int atomics, L2-resident)
//  3. scan1:  per-block (2048) reduce -> blockSums
//  4. scan2:  single-block scan of blockSums (nb<=256), offsets[n_vox]=total
//  5. scan3:  per-block exclusive scan -> offsets; cursor=offsets
//  6. fill:   plist[atomicAdd(cursor[v])] = point_id
//  7. fused:  one wave per voxel. Read v row (1 ch/lane), lane-parallel load
//             of all point ids, 1-deep software-pipelined loop over points:
//             row load -> gate MLP (12-shfl wave reduce) -> softmax -> fuse
//             write + register accumulate -> v_new = acc/max(count,1).
//             Zero divergence (all lanes same voxel), loads off critical path.
// ---------------------------------------------------------------------------

static const int SCAN_ELEMS = 2048;   // 256 threads x 8

__global__ __launch_bounds__(256) void hist_kernel(
    const int* __restrict__ p2v, int* __restrict__ counts, int n)
{
    int i = blockIdx.x * blockDim.x + threadIdx.x;
    if (i < n) atomicAdd(&counts[p2v[i]], 1);
}

__global__ __launch_bounds__(256) void scan1_kernel(
    const int* __restrict__ counts, int* __restrict__ blockSums, int n)
{
    const int base = blockIdx.x * SCAN_ELEMS;
    const int tid = threadIdx.x;
    int s = 0;
    const int i0 = base + tid * 8;
    #pragma unroll
    for (int j = 0; j < 8; j++) {
        int idx = i0 + j;
        s += (idx < n) ? counts[idx] : 0;
    }
    #pragma unroll
    for (int m = 1; m < 64; m <<= 1) s += __shfl_xor(s, m);
    __shared__ int wsum[4];
    const int lane = tid & 63, wave = tid >> 6;
    if (lane == 0) wsum[wave] = s;
    __syncthreads();
    if (tid == 0) blockSums[blockIdx.x] = wsum[0] + wsum[1] + wsum[2] + wsum[3];
}

__global__ __launch_bounds__(256) void scan2_kernel(
    int* __restrict__ blockSums, int* __restrict__ offsets, int nb, int n_vox)
{
    __shared__ int sh[256];
    const int tid = threadIdx.x;
    const int v = (tid < nb) ? blockSums[tid] : 0;
    sh[tid] = v;
    __syncthreads();
    #pragma unroll
    for (int off = 1; off < 256; off <<= 1) {
        int t = (tid >= off) ? sh[tid - off] : 0;
        __syncthreads();
        sh[tid] += t;
        __syncthreads();
    }
    if (tid < nb) blockSums[tid] = sh[tid] - v;   // exclusive
    if (tid == 255) offsets[n_vox] = sh[255];     // total = n_pts
}

__global__ __launch_bounds__(256) void scan3_kernel(
    const int* __restrict__ counts, const int* __restrict__ blockSums,
    int* __restrict__ offsets, int* __restrict__ cursor, int n)
{
    const int base = blockIdx.x * SCAN_ELEMS;
    const int tid = threadIdx.x;
    const int i0 = base + tid * 8;
    int vals[8];
    #pragma unroll
    for (int j = 0; j < 8; j++) {
        int idx = i0 + j;
        vals[j] = (idx < n) ? counts[idx] : 0;
    }
    int s = 0;
    #pragma unroll
    for (int j = 0; j < 8; j++) s += vals[j];

    const int lane = tid & 63, wave = tid >> 6;
    int incl = s;
    #pragma unroll
    for (int off = 1; off < 64; off <<= 1) {
        int t = __shfl_up(incl, off);
        if (lane >= off) incl += t;
    }
    __shared__ int wsum[4];
    if (lane == 63) wsum[wave] = incl;
    __syncthreads();
    int wbase = 0;
    for (int w = 0; w < 4; w++) wbase += (w < wave) ? wsum[w] : 0;

    int run = incl - s + wbase + blockSums[blockIdx.x];
    #pragma unroll
    for (int j = 0; j < 8; j++) {
        int idx = i0 + j;
        if (idx < n) { offsets[idx] = run; cursor[idx] = run; }
        run += vals[j];
    }
}

__global__ __launch_bounds__(256) void fill_kernel(
    const int* __restrict__ p2v, int* __restrict__ cursor,
    int* __restrict__ plist, int n)
{
    int i = blockIdx.x * blockDim.x + threadIdx.x;
    if (i < n) {
        int v = p2v[i];
        int pos = atomicAdd(&cursor[v], 1);
        plist[pos] = i;
    }
}

__global__ __launch_bounds__(256) void fused_kernel(
    const float* __restrict__ p_feats, const float* __restrict__ v_feats,
    const float* __restrict__ Wp, const float* __restrict__ bp,
    const float* __restrict__ Wv, const float* __restrict__ bv,
    const int* __restrict__ offsets, const int* __restrict__ plist,
    float* __restrict__ fuse_out, float* __restrict__ v_new, int n_vox)
{
    const int gtid = blockIdx.x * blockDim.x + threadIdx.x;
    const int v = gtid >> 6;            // one wave per voxel
    const int lane = threadIdx.x & 63;  // lane = channel
    if (v >= n_vox) return;

    // Wp/Wv are [C,2] row-major: lane's channel weights at [2*lane, 2*lane+1]
    const float wp0 = Wp[2 * lane], wp1 = Wp[2 * lane + 1];
    const float wv0 = Wv[2 * lane], wv1 = Wv[2 * lane + 1];
    const float bias0 = bp[0] + bv[0];
    const float bias1 = bp[1] + bv[1];

    // voxel feature: 1 channel per lane, read once
    const float vf = v_feats[(size_t)v * C + lane];

    // v-side logit contribution (wave reduce, once per voxel)
    float lv0 = vf * wv0, lv1 = vf * wv1;
    #pragma unroll
    for (int m = 1; m < 64; m <<= 1) {
        lv0 += __shfl_xor(lv0, m);
        lv1 += __shfl_xor(lv1, m);
    }
    lv0 += bias0;
    lv1 += bias1;

    const int beg = offsets[v], end = offsets[v + 1];
    float acc = 0.f;

    for (int base = beg; base < end; base += 64) {
        const int cnt = min(64, end - base);
        // lane-parallel load of up to 64 point ids (one instruction)
        const int pid_l = (base + lane < end) ? plist[base + lane] : 0;

        // 1-deep software pipeline: row load issued before previous compute
        int pid_next = __shfl(pid_l, 0);
        float pf_next = p_feats[(size_t)pid_next * C + lane];

        for (int i = 0; i < cnt; i++) {
            const int pid = pid_next;
            const float pf = pf_next;
            if (i + 1 < cnt) {
                pid_next = __shfl(pid_l, i + 1);
                pf_next = p_feats[(size_t)pid_next * C + lane];
            }

            float l0 = pf * wp0, l1 = pf * wp1;
            #pragma unroll
            for (int m = 1; m < 64; m <<= 1) {
                l0 += __shfl_xor(l0, m);
                l1 += __shfl_xor(l1, m);
            }
            l0 += lv0;
            l1 += lv1;

            const float mx = fmaxf(l0, l1);
            const float e0 = __expf(l0 - mx), e1 = __expf(l1 - mx);
            const float w0 = e0 / (e0 + e1);
            const float w1 = 1.0f - w0;

            const float f = pf * w0 + vf * w1;
            fuse_out[(size_t)pid * C + lane] = f;
            acc += f;
        }
    }

    v_new[(size_t)v * C + lane] = acc / (float)max(end - beg, 1);
}

extern "C" void kernel_launch(void* const* d_in, const int* in_sizes, int n_in,
                              void* d_out, int out_size, void* d_ws, size_t ws_size,
                              hipStream_t stream) {
    const float* p_feats = (const float*)d_in[0];
    const float* v_feats = (const float*)d_in[1];
    const float* Wp = (const float*)d_in[2];
    const float* bp = (const float*)d_in[3];
    const float* Wv = (const float*)d_in[4];
    const float* bv = (const float*)d_in[5];
    const int* p2v = (const int*)d_in[6];

    const int n_pts = in_sizes[0] / C;
    const int n_vox = in_sizes[1] / C;

    float* fuse_out = (float*)d_out;
    float* v_new = fuse_out + (size_t)n_pts * C;

    // workspace layout (ints)
    int* offsets = (int*)d_ws;                        // n_vox+1
    int* counts = offsets + (n_vox + 1);              // n_vox (reused as cursor)
    int* blockSums = counts + n_vox;                  // 256
    int* plist = blockSums + 256;                     // n_pts

    const int nb = (n_vox + SCAN_ELEMS - 1) / SCAN_ELEMS;
    const int T = 256;

    hipMemsetAsync(counts, 0, (size_t)n_vox * sizeof(int), stream);
    hist_kernel<<<(n_pts + T - 1) / T, T, 0, stream>>>(p2v, counts, n_pts);
    scan1_kernel<<<nb, T, 0, stream>>>(counts, blockSums, n_vox);
    scan2_kernel<<<1, T, 0, stream>>>(blockSums, offsets, nb, n_vox);
    scan3_kernel<<<nb, T, 0, stream>>>(counts, blockSums, offsets, counts, n_vox);
    fill_kernel<<<(n_pts + T - 1) / T, T, 0, stream>>>(p2v, counts, plist, n_pts);

    fused_kernel<<<((size_t)n_vox * 64 + T - 1) / T, T, 0, stream>>>(
        p_feats, v_feats, Wp, bp, Wv, bv, offsets, plist,
        fuse_out, v_new, n_vox);
}

// Round 5
// 539.033 us; speedup vs baseline: 1.3978x; 1.3978x over previous
//
#include <hip/hip_runtime.h>

#define C 64
#define SCAN_ELEMS 2048   // 256 threads x 8 elements

// ---------------------------------------------------------------------------
// 5 dispatches total:
//  1. memset  counts[n_vox] + stat[nb]           (one contiguous region)
//  2. hist:   counts[v]++ per point              (int atomics, L2-resident)
//  3. scan:   ONE decoupled-lookback kernel      -> offsets, cursor, total
//  4. fill:   plist[atomicAdd(cursor[v])] = pid  (CSR point lists)
//  5. fused:  16 threads/voxel (4ch each, DPP shfl reduce), 2-deep
//             software-pipelined loop over the voxel's points:
//             row load -> gate MLP -> softmax -> fuse write + reg accumulate
//             -> v_new = acc/max(cnt,1).   (min traffic, no float atomics)
// ---------------------------------------------------------------------------

static __device__ __forceinline__ int ld_acq(const int* p) {
    return __hip_atomic_load(p, __ATOMIC_ACQUIRE, __HIP_MEMORY_SCOPE_AGENT);
}
static __device__ __forceinline__ int ld_rlx(const int* p) {
    return __hip_atomic_load(p, __ATOMIC_RELAXED, __HIP_MEMORY_SCOPE_AGENT);
}
static __device__ __forceinline__ void st_rel(int* p, int v) {
    __hip_atomic_store(p, v, __ATOMIC_RELEASE, __HIP_MEMORY_SCOPE_AGENT);
}

__global__ __launch_bounds__(256) void hist_kernel(
    const int* __restrict__ p2v, int* __restrict__ counts, int n)
{
    int i = blockIdx.x * blockDim.x + threadIdx.x;
    if (i < n) atomicAdd(&counts[p2v[i]], 1);
}

// Single-pass exclusive scan with decoupled lookback.
// stat[b]: 0=invalid, 1=aggregate ready, 2=prefix ready.
__global__ __launch_bounds__(256) void scan_kernel(
    const int* __restrict__ counts, int* __restrict__ offsets,
    int* __restrict__ cursor, int* __restrict__ agg, int* __restrict__ pref,
    int* __restrict__ stat, int n, int nb)
{
    const int b = blockIdx.x, tid = threadIdx.x;
    const int i0 = b * SCAN_ELEMS + tid * 8;

    int vals[8];
    #pragma unroll
    for (int j = 0; j < 8; j++) {
        int idx = i0 + j;
        vals[j] = (idx < n) ? counts[idx] : 0;
    }
    int s = 0;
    #pragma unroll
    for (int j = 0; j < 8; j++) s += vals[j];

    const int lane = tid & 63, wave = tid >> 6;
    int incl = s;
    #pragma unroll
    for (int off = 1; off < 64; off <<= 1) {
        int t = __shfl_up(incl, off);
        if (lane >= off) incl += t;
    }
    __shared__ int wsum[4];
    if (lane == 63) wsum[wave] = incl;
    __syncthreads();
    int wbase = 0;
    #pragma unroll
    for (int w = 0; w < 4; w++) wbase += (w < wave) ? wsum[w] : 0;
    const int blockAgg = wsum[0] + wsum[1] + wsum[2] + wsum[3];

    // publish aggregate
    if (tid == 0 && b > 0) {
        agg[b] = blockAgg;          // ordered before stat by release below
        st_rel(&stat[b], 1);
    }

    // lookback by wave 0
    __shared__ int s_pref;
    if (wave == 0) {
        if (b == 0) {
            if (lane == 0) {
                s_pref = 0;
                pref[0] = blockAgg;
                st_rel(&stat[0], 2);
            }
        } else {
            int sum = 0;
            int j = b - 1;
            for (;;) {
                const int k = j - lane;
                int st, a = 0, p = 0;
                if (k < 0) {
                    st = 2;                      // sentinel: prefix 0
                } else {
                    st = ld_acq(&stat[k]);
                    while (st == 0) st = ld_acq(&stat[k]);
                    if (st == 2) p = ld_rlx(&pref[k]);
                    else         a = ld_rlx(&agg[k]);
                }
                const unsigned long long m = __ballot(st == 2);
                if (m) {
                    const int fl = (int)(__ffsll((long long)m) - 1);
                    int contrib = (lane < fl) ? a : ((lane == fl) ? p : 0);
                    #pragma unroll
                    for (int off = 1; off < 64; off <<= 1)
                        contrib += __shfl_xor(contrib, off);
                    sum += contrib;
                    break;
                } else {
                    int contrib = a;
                    #pragma unroll
                    for (int off = 1; off < 64; off <<= 1)
                        contrib += __shfl_xor(contrib, off);
                    sum += contrib;
                    j -= 64;
                }
            }
            if (lane == 0) {
                s_pref = sum;
                pref[b] = sum + blockAgg;
                st_rel(&stat[b], 2);
            }
        }
    }
    __syncthreads();
    const int ex0 = s_pref;

    int run = ex0 + wbase + (incl - s);
    #pragma unroll
    for (int j = 0; j < 8; j++) {
        int idx = i0 + j;
        if (idx < n) { offsets[idx] = run; cursor[idx] = run; }
        run += vals[j];
    }
    if (b == nb - 1 && tid == 0) offsets[n] = ex0 + blockAgg;
}

__global__ __launch_bounds__(256) void fill_kernel(
    const int* __restrict__ p2v, int* __restrict__ cursor,
    int* __restrict__ plist, int n)
{
    int i = blockIdx.x * blockDim.x + threadIdx.x;
    if (i < n) {
        int v = p2v[i];
        int pos = atomicAdd(&cursor[v], 1);
        plist[pos] = i;
    }
}

__global__ __launch_bounds__(256) void fused_kernel(
    const float* __restrict__ p_feats, const float* __restrict__ v_feats,
    const float* __restrict__ Wp, const float* __restrict__ bp,
    const float* __restrict__ Wv, const float* __restrict__ bv,
    const int* __restrict__ offsets, const int* __restrict__ plist,
    float* __restrict__ fuse_out, float* __restrict__ v_new, int n_vox)
{
    const int gid = blockIdx.x * blockDim.x + threadIdx.x;
    const int v = gid >> 4;          // 16 threads per voxel
    const int t = gid & 15;          // 4 channels per thread
    if (v >= n_vox) return;

    // Wp/Wv are [C,2] row-major; thread t needs rows 4t..4t+3 => two float4s
    const float4* Wp4 = (const float4*)Wp;
    const float4* Wv4 = (const float4*)Wv;
    const float4 wpA = Wp4[2 * t], wpB = Wp4[2 * t + 1];
    const float4 wvA = Wv4[2 * t], wvB = Wv4[2 * t + 1];
    const float bias0 = bp[0] + bv[0];
    const float bias1 = bp[1] + bv[1];

    // voxel feature row: read once, reuse for all its points
    const float4 vf = *(const float4*)(v_feats + (size_t)v * C + t * 4);

    // v-side logit contribution (4-step DPP shfl reduce, once per voxel)
    float lv0 = vf.x * wvA.x + vf.y * wvA.z + vf.z * wvB.x + vf.w * wvB.z;
    float lv1 = vf.x * wvA.y + vf.y * wvA.w + vf.z * wvB.y + vf.w * wvB.w;
    #pragma unroll
    for (int m = 1; m < 16; m <<= 1) {
        lv0 += __shfl_xor(lv0, m);
        lv1 += __shfl_xor(lv1, m);
    }
    lv0 += bias0;
    lv1 += bias1;

    const int beg = offsets[v];
    const int n = offsets[v + 1] - beg;
    float4 acc = make_float4(0.f, 0.f, 0.f, 0.f);

    // 2-deep software pipeline over the voxel's points
    int pidA = 0, pidB = 0;
    float4 pfA = make_float4(0.f, 0.f, 0.f, 0.f), pfB = pfA;
    if (n > 0) {
        pidA = plist[beg];
        pfA = *(const float4*)(p_feats + (size_t)pidA * C + t * 4);
    }
    if (n > 1) {
        pidB = plist[beg + 1];
        pfB = *(const float4*)(p_feats + (size_t)pidB * C + t * 4);
    }

    for (int i = 0; i < n; i++) {
        const int pid = pidA;
        const float4 pf = pfA;
        pidA = pidB; pfA = pfB;
        if (i + 2 < n) {
            pidB = plist[beg + i + 2];
            pfB = *(const float4*)(p_feats + (size_t)pidB * C + t * 4);
        }

        float l0 = pf.x * wpA.x + pf.y * wpA.z + pf.z * wpB.x + pf.w * wpB.z;
        float l1 = pf.x * wpA.y + pf.y * wpA.w + pf.z * wpB.y + pf.w * wpB.w;
        #pragma unroll
        for (int m = 1; m < 16; m <<= 1) {
            l0 += __shfl_xor(l0, m);
            l1 += __shfl_xor(l1, m);
        }
        l0 += lv0;
        l1 += lv1;

        const float mx = fmaxf(l0, l1);
        const float e0 = __expf(l0 - mx), e1 = __expf(l1 - mx);
        const float w0 = e0 / (e0 + e1);
        const float w1 = 1.0f - w0;

        float4 f;
        f.x = pf.x * w0 + vf.x * w1;
        f.y = pf.y * w0 + vf.y * w1;
        f.z = pf.z * w0 + vf.z * w1;
        f.w = pf.w * w0 + vf.w * w1;

        *(float4*)(fuse_out + (size_t)pid * C + t * 4) = f;
        acc.x += f.x; acc.y += f.y; acc.z += f.z; acc.w += f.w;
    }

    const float inv = 1.0f / (float)max(n, 1);
    float4 r;
    r.x = acc.x * inv; r.y = acc.y * inv; r.z = acc.z * inv; r.w = acc.w * inv;
    *(float4*)(v_new + (size_t)v * C + t * 4) = r;
}

extern "C" void kernel_launch(void* const* d_in, const int* in_sizes, int n_in,
                              void* d_out, int out_size, void* d_ws, size_t ws_size,
                              hipStream_t stream) {
    const float* p_feats = (const float*)d_in[0];
    const float* v_feats = (const float*)d_in[1];
    const float* Wp = (const float*)d_in[2];
    const float* bp = (const float*)d_in[3];
    const float* Wv = (const float*)d_in[4];
    const float* bv = (const float*)d_in[5];
    const int* p2v = (const int*)d_in[6];

    const int n_pts = in_sizes[0] / C;
    const int n_vox = in_sizes[1] / C;
    const int nb = (n_vox + SCAN_ELEMS - 1) / SCAN_ELEMS;

    float* fuse_out = (float*)d_out;
    float* v_new = fuse_out + (size_t)n_pts * C;

    // workspace layout (ints): [counts n_vox][stat nb] <- zeroed together
    //                          [agg nb][pref nb][offsets n_vox+1][cursor n_vox][plist n_pts]
    int* counts = (int*)d_ws;
    int* stat = counts + n_vox;
    int* agg = stat + nb;
    int* pref = agg + nb;
    int* offsets = pref + nb;
    int* cursor = offsets + (n_vox + 1);
    int* plist = cursor + n_vox;

    const int T = 256;

    hipMemsetAsync(counts, 0, (size_t)(n_vox + nb) * sizeof(int), stream);
    hist_kernel<<<(n_pts + T - 1) / T, T, 0, stream>>>(p2v, counts, n_pts);
    scan_kernel<<<nb, T, 0, stream>>>(counts, offsets, cursor, agg, pref, stat,
                                      n_vox, nb);
    fill_kernel<<<(n_pts + T - 1) / T, T, 0, stream>>>(p2v, cursor, plist, n_pts);
    fused_kernel<<<((size_t)n_vox * 16 + T - 1) / T, T, 0, stream>>>(
        p_feats, v_feats, Wp, bp, Wv, bv, offsets, plist,
        fuse_out, v_new, n_vox);
}

// Round 6
// 528.390 us; speedup vs baseline: 1.4260x; 1.0201x over previous
//
#include <hip/hip_runtime.h>

#define C 64
#define SCAN_ELEMS 2048   // 256 threads x 8 elements

typedef float f4 __attribute__((ext_vector_type(4)));

// ---------------------------------------------------------------------------
// 5 dispatches, all named (full rocprof attribution):
//  1. zero:   counts[n_vox] + stat[nb] = 0      (custom kernel, no rocclr fill)
//  2. hist:   counts[v]++ per point             (int atomics, L2-resident)
//  3. scan:   decoupled-lookback exclusive scan -> offsets, cursor, total
//  4. fill:   plist[atomicAdd(cursor[v])] = pid (CSR point lists)
//  5. fused:  16 threads/voxel (4ch each), 3-deep software-pipelined loop:
//             nt-load p_feats row -> gate MLP (DPP shfl reduce) -> softmax ->
//             nt-store fuse row + reg accumulate -> v_new = acc/max(cnt,1)
// ---------------------------------------------------------------------------

static __device__ __forceinline__ int ld_acq(const int* p) {
    return __hip_atomic_load(p, __ATOMIC_ACQUIRE, __HIP_MEMORY_SCOPE_AGENT);
}
static __device__ __forceinline__ int ld_rlx(const int* p) {
    return __hip_atomic_load(p, __ATOMIC_RELAXED, __HIP_MEMORY_SCOPE_AGENT);
}
static __device__ __forceinline__ void st_rel(int* p, int v) {
    __hip_atomic_store(p, v, __ATOMIC_RELEASE, __HIP_MEMORY_SCOPE_AGENT);
}

__global__ __launch_bounds__(256) void zero_kernel(int* __restrict__ p, int n)
{
    int i = blockIdx.x * blockDim.x + threadIdx.x;
    if (i < n) p[i] = 0;
}

__global__ __launch_bounds__(256) void hist_kernel(
    const int* __restrict__ p2v, int* __restrict__ counts, int n)
{
    int i = blockIdx.x * blockDim.x + threadIdx.x;
    if (i < n) atomicAdd(&counts[p2v[i]], 1);
}

// Single-pass exclusive scan with decoupled lookback.
// stat[b]: 0=invalid, 1=aggregate ready, 2=prefix ready.
__global__ __launch_bounds__(256) void scan_kernel(
    const int* __restrict__ counts, int* __restrict__ offsets,
    int* __restrict__ cursor, int* __restrict__ agg, int* __restrict__ pref,
    int* __restrict__ stat, int n, int nb)
{
    const int b = blockIdx.x, tid = threadIdx.x;
    const int i0 = b * SCAN_ELEMS + tid * 8;

    int vals[8];
    #pragma unroll
    for (int j = 0; j < 8; j++) {
        int idx = i0 + j;
        vals[j] = (idx < n) ? counts[idx] : 0;
    }
    int s = 0;
    #pragma unroll
    for (int j = 0; j < 8; j++) s += vals[j];

    const int lane = tid & 63, wave = tid >> 6;
    int incl = s;
    #pragma unroll
    for (int off = 1; off < 64; off <<= 1) {
        int t = __shfl_up(incl, off);
        if (lane >= off) incl += t;
    }
    __shared__ int wsum[4];
    if (lane == 63) wsum[wave] = incl;
    __syncthreads();
    int wbase = 0;
    #pragma unroll
    for (int w = 0; w < 4; w++) wbase += (w < wave) ? wsum[w] : 0;
    const int blockAgg = wsum[0] + wsum[1] + wsum[2] + wsum[3];

    if (tid == 0 && b > 0) {
        agg[b] = blockAgg;
        st_rel(&stat[b], 1);
    }

    __shared__ int s_pref;
    if (wave == 0) {
        if (b == 0) {
            if (lane == 0) {
                s_pref = 0;
                pref[0] = blockAgg;
                st_rel(&stat[0], 2);
            }
        } else {
            int sum = 0;
            int j = b - 1;
            for (;;) {
                const int k = j - lane;
                int st, a = 0, p = 0;
                if (k < 0) {
                    st = 2;                      // sentinel: prefix 0
                } else {
                    st = ld_acq(&stat[k]);
                    while (st == 0) st = ld_acq(&stat[k]);
                    if (st == 2) p = ld_rlx(&pref[k]);
                    else         a = ld_rlx(&agg[k]);
                }
                const unsigned long long m = __ballot(st == 2);
                if (m) {
                    const int fl = (int)(__ffsll((long long)m) - 1);
                    int contrib = (lane < fl) ? a : ((lane == fl) ? p : 0);
                    #pragma unroll
                    for (int off = 1; off < 64; off <<= 1)
                        contrib += __shfl_xor(contrib, off);
                    sum += contrib;
                    break;
                } else {
                    int contrib = a;
                    #pragma unroll
                    for (int off = 1; off < 64; off <<= 1)
                        contrib += __shfl_xor(contrib, off);
                    sum += contrib;
                    j -= 64;
                }
            }
            if (lane == 0) {
                s_pref = sum;
                pref[b] = sum + blockAgg;
                st_rel(&stat[b], 2);
            }
        }
    }
    __syncthreads();
    const int ex0 = s_pref;

    int run = ex0 + wbase + (incl - s);
    #pragma unroll
    for (int j = 0; j < 8; j++) {
        int idx = i0 + j;
        if (idx < n) { offsets[idx] = run; cursor[idx] = run; }
        run += vals[j];
    }
    if (b == nb - 1 && tid == 0) offsets[n] = ex0 + blockAgg;
}

__global__ __launch_bounds__(256) void fill_kernel(
    const int* __restrict__ p2v, int* __restrict__ cursor,
    int* __restrict__ plist, int n)
{
    int i = blockIdx.x * blockDim.x + threadIdx.x;
    if (i < n) {
        int v = p2v[i];
        int pos = atomicAdd(&cursor[v], 1);
        plist[pos] = i;
    }
}

__global__ __launch_bounds__(256) void fused_kernel(
    const float* __restrict__ p_feats, const float* __restrict__ v_feats,
    const float* __restrict__ Wp, const float* __restrict__ bp,
    const float* __restrict__ Wv, const float* __restrict__ bv,
    const int* __restrict__ offsets, const int* __restrict__ plist,
    float* __restrict__ fuse_out, float* __restrict__ v_new, int n_vox)
{
    const int gid = blockIdx.x * blockDim.x + threadIdx.x;
    const int v = gid >> 4;          // 16 threads per voxel
    const int t = gid & 15;          // 4 channels per thread
    if (v >= n_vox) return;

    // Wp/Wv are [C,2] row-major; thread t needs rows 4t..4t+3 => two float4s
    const f4* Wp4 = (const f4*)Wp;
    const f4* Wv4 = (const f4*)Wv;
    const f4 wpA = Wp4[2 * t], wpB = Wp4[2 * t + 1];
    const f4 wvA = Wv4[2 * t], wvB = Wv4[2 * t + 1];
    const float bias0 = bp[0] + bv[0];
    const float bias1 = bp[1] + bv[1];

    // voxel feature row: read once, reuse for all its points
    const f4 vf = *(const f4*)(v_feats + (size_t)v * C + t * 4);

    // v-side logit contribution (4-step DPP shfl reduce, once per voxel)
    float lv0 = vf.x * wvA.x + vf.y * wvA.z + vf.z * wvB.x + vf.w * wvB.z;
    float lv1 = vf.x * wvA.y + vf.y * wvA.w + vf.z * wvB.y + vf.w * wvB.w;
    #pragma unroll
    for (int m = 1; m < 16; m <<= 1) {
        lv0 += __shfl_xor(lv0, m);
        lv1 += __shfl_xor(lv1, m);
    }
    lv0 += bias0;
    lv1 += bias1;

    const int beg = offsets[v];
    const int n = offsets[v + 1] - beg;
    f4 acc = (f4){0.f, 0.f, 0.f, 0.f};

    // 3-deep software pipeline over the voxel's points (nontemporal row loads:
    // p_feats rows have zero reuse — keep L2 for v_feats/plist/offsets)
    int pidA = 0, pidB = 0, pidC = 0;
    f4 pfA = (f4){0.f, 0.f, 0.f, 0.f}, pfB = pfA, pfC = pfA;
    if (n > 0) {
        pidA = plist[beg];
        pfA = __builtin_nontemporal_load((const f4*)(p_feats + (size_t)pidA * C + t * 4));
    }
    if (n > 1) {
        pidB = plist[beg + 1];
        pfB = __builtin_nontemporal_load((const f4*)(p_feats + (size_t)pidB * C + t * 4));
    }
    if (n > 2) {
        pidC = plist[beg + 2];
        pfC = __builtin_nontemporal_load((const f4*)(p_feats + (size_t)pidC * C + t * 4));
    }

    for (int i = 0; i < n; i++) {
        const int pid = pidA;
        const f4 pf = pfA;
        pidA = pidB; pfA = pfB;
        pidB = pidC; pfB = pfC;
        if (i + 3 < n) {
            pidC = plist[beg + i + 3];
            pfC = __builtin_nontemporal_load((const f4*)(p_feats + (size_t)pidC * C + t * 4));
        }

        float l0 = pf.x * wpA.x + pf.y * wpA.z + pf.z * wpB.x + pf.w * wpB.z;
        float l1 = pf.x * wpA.y + pf.y * wpA.w + pf.z * wpB.y + pf.w * wpB.w;
        #pragma unroll
        for (int m = 1; m < 16; m <<= 1) {
            l0 += __shfl_xor(l0, m);
            l1 += __shfl_xor(l1, m);
        }
        l0 += lv0;
        l1 += lv1;

        const float mx = fmaxf(l0, l1);
        const float e0 = __expf(l0 - mx), e1 = __expf(l1 - mx);
        const float w0 = e0 / (e0 + e1);
        const float w1 = 1.0f - w0;

        f4 f;
        f.x = pf.x * w0 + vf.x * w1;
        f.y = pf.y * w0 + vf.y * w1;
        f.z = pf.z * w0 + vf.z * w1;
        f.w = pf.w * w0 + vf.w * w1;

        __builtin_nontemporal_store(f, (f4*)(fuse_out + (size_t)pid * C + t * 4));
        acc.x += f.x; acc.y += f.y; acc.z += f.z; acc.w += f.w;
    }

    const float inv = 1.0f / (float)max(n, 1);
    f4 r;
    r.x = acc.x * inv; r.y = acc.y * inv; r.z = acc.z * inv; r.w = acc.w * inv;
    *(f4*)(v_new + (size_t)v * C + t * 4) = r;
}

extern "C" void kernel_launch(void* const* d_in, const int* in_sizes, int n_in,
                              void* d_out, int out_size, void* d_ws, size_t ws_size,
                              hipStream_t stream) {
    const float* p_feats = (const float*)d_in[0];
    const float* v_feats = (const float*)d_in[1];
    const float* Wp = (const float*)d_in[2];
    const float* bp = (const float*)d_in[3];
    const float* Wv = (const float*)d_in[4];
    const float* bv = (const float*)d_in[5];
    const int* p2v = (const int*)d_in[6];

    const int n_pts = in_sizes[0] / C;
    const int n_vox = in_sizes[1] / C;
    const int nb = (n_vox + SCAN_ELEMS - 1) / SCAN_ELEMS;

    float* fuse_out = (float*)d_out;
    float* v_new = fuse_out + (size_t)n_pts * C;

    // workspace layout (ints): [counts n_vox][stat nb] <- zeroed together
    //                          [agg nb][pref nb][offsets n_vox+1][cursor n_vox][plist n_pts]
    int* counts = (int*)d_ws;
    int* stat = counts + n_vox;
    int* agg = stat + nb;
    int* pref = agg + nb;
    int* offsets = pref + nb;
    int* cursor = offsets + (n_vox + 1);
    int* plist = cursor + n_vox;

    const int T = 256;

    zero_kernel<<<(n_vox + nb + T - 1) / T, T, 0, stream>>>(counts, n_vox + nb);
    hist_kernel<<<(n_pts + T - 1) / T, T, 0, stream>>>(p2v, counts, n_pts);
    scan_kernel<<<nb, T, 0, stream>>>(counts, offsets, cursor, agg, pref, stat,
                                      n_vox, nb);
    fill_kernel<<<(n_pts + T - 1) / T, T, 0, stream>>>(p2v, cursor, plist, n_pts);
    fused_kernel<<<((size_t)n_vox * 16 + T - 1) / T, T, 0, stream>>>(
        p_feats, v_feats, Wp, bp, Wv, bv, offsets, plist,
        fuse_out, v_new, n_vox);
}